// Round 1
// baseline (843.239 us; speedup 1.0000x reference)
//
#include <hip/hip_runtime.h>
#include <cstdint>

typedef __attribute__((ext_vector_type(8))) short short8;
typedef __attribute__((ext_vector_type(16))) float f32x16;

#define B_   32
#define IN_  2048
#define ID_  16
#define ON_  64
#define OD_  32
// weight strides (floats): o: 2048*32*16 = 1048576, i: 512, d: 16, k: 1

__device__ __forceinline__ unsigned short f2bf(float f) {
    union { float f; uint32_t u; } c; c.f = f;
    uint32_t u = c.u;
    uint32_t r = (u + 0x7FFFu + ((u >> 16) & 1u)) >> 16;
    return (unsigned short)r;
}
__device__ __forceinline__ unsigned int pack2(float a, float b) {
    return (unsigned int)f2bf(a) | ((unsigned int)f2bf(b) << 16);
}

// ---------------- Pass 0: S0[b][o][d] = sum_i x_hat[b,o,i,d] ----------------
// grid: 1024 = 4 o-groups x 256 i-chunks (IC=8), block 256 (4 waves, 4 o per wave)
__global__ __launch_bounds__(256, 4) void pass0_k(
    const float* __restrict__ x, const float* __restrict__ w, float* __restrict__ S)
{
    __shared__ __align__(16) unsigned short lw[16 * 512];  // 16 o x 512 bf16
    __shared__ __align__(16) unsigned short lx[512];       // 32 b x 16 k bf16

    const int t = threadIdx.x, lane = t & 63, wv = t >> 6;
    const int bx = blockIdx.x;
    const int ic = bx & 255, og = bx >> 8;
    const int o0 = og * 16;
    const int d = lane & 31, half = lane >> 5;

    f32x16 acc[4] = {};

    for (int i = ic * 8; i < ic * 8 + 8; ++i) {
        // stage weight: 16 o * 64 chunks(8 el) = 1024 chunks
        #pragma unroll
        for (int r = 0; r < 4; ++r) {
            int cidx = r * 256 + t;
            int ol = cidx >> 6, j8 = cidx & 63;
            const float* g = w + (size_t)(o0 + ol) * 1048576 + (size_t)i * 512 + j8 * 8;
            float4 a = *(const float4*)g;
            float4 b2 = *(const float4*)(g + 4);
            uint4 val = { pack2(a.x, a.y), pack2(a.z, a.w), pack2(b2.x, b2.y), pack2(b2.z, b2.w) };
            *reinterpret_cast<uint4*>(&lw[ol * 512 + j8 * 8]) = val;
        }
        if (t < 128) {
            int b = t >> 2, kq = t & 3;
            float4 a = *(const float4*)(x + ((size_t)b * IN_ + i) * ID_ + kq * 4);
            uint2 val = { pack2(a.x, a.y), pack2(a.z, a.w) };
            *reinterpret_cast<uint2*>(&lx[b * 16 + kq * 4]) = val;
        }
        __syncthreads();

        short8 afr = *reinterpret_cast<const short8*>(&lx[(lane & 31) * 16 + half * 8]);
        #pragma unroll
        for (int oi = 0; oi < 4; ++oi) {
            int ol = wv * 4 + oi;
            short8 bfr = *reinterpret_cast<const short8*>(&lw[ol * 512 + d * 16 + half * 8]);
            acc[oi] = __builtin_amdgcn_mfma_f32_32x32x16_bf16(afr, bfr, acc[oi], 0, 0, 0);
        }
        __syncthreads();
    }

    #pragma unroll
    for (int oi = 0; oi < 4; ++oi) {
        int o = o0 + wv * 4 + oi;
        #pragma unroll
        for (int r = 0; r < 16; ++r) {
            int b = (r & 3) + 8 * (r >> 2) + 4 * half;
            atomicAdd(&S[((size_t)b * ON_ + o) * OD_ + d], acc[oi][r]);
        }
    }
}

// ---------------- Routing pass: S[b][o][d] += softmax_o(dot(v,xhat)) * xhat --
// grid: 256 i-chunks (IC=8), block 512 (8 waves, 8 o per wave)
__global__ __launch_bounds__(512, 2) void pass_route_k(
    const float* __restrict__ x, const float* __restrict__ w,
    const float* __restrict__ vin /* [o][b][d] */, float* __restrict__ S)
{
    __shared__ __align__(16) unsigned short lw[64 * 512];  // 64 KB
    __shared__ __align__(16) unsigned short lx[512];       // 1 KB
    __shared__ float blds[B_ * ON_];                       // [b][o] 8 KB
    __shared__ float clds[B_ * ON_];                       // 8 KB

    const int t = threadIdx.x, lane = t & 63, wv = t >> 6;  // 8 waves
    const int ic = blockIdx.x;
    const int d = lane & 31, half = lane >> 5;

    f32x16 acc[8] = {};

    for (int i = ic * 8; i < ic * 8 + 8; ++i) {
        // stage weight: 64 o * 64 chunks = 4096 chunks, 512 thr -> 8 iters
        #pragma unroll
        for (int r = 0; r < 8; ++r) {
            int cidx = r * 512 + t;
            int ol = cidx >> 6, j8 = cidx & 63;
            const float* g = w + (size_t)ol * 1048576 + (size_t)i * 512 + j8 * 8;
            float4 a = *(const float4*)g;
            float4 b2 = *(const float4*)(g + 4);
            uint4 val = { pack2(a.x, a.y), pack2(a.z, a.w), pack2(b2.x, b2.y), pack2(b2.z, b2.w) };
            *reinterpret_cast<uint4*>(&lw[ol * 512 + j8 * 8]) = val;
        }
        if (t < 128) {
            int b = t >> 2, kq = t & 3;
            float4 a = *(const float4*)(x + ((size_t)b * IN_ + i) * ID_ + kq * 4);
            uint2 val = { pack2(a.x, a.y), pack2(a.z, a.w) };
            *reinterpret_cast<uint2*>(&lx[b * 16 + kq * 4]) = val;
        }
        __syncthreads();

        short8 afr = *reinterpret_cast<const short8*>(&lx[(lane & 31) * 16 + half * 8]);
        short8 bfr[8];

        // phase A: compute logits b[b,o] = dot(v[b,o,:], xhat[b,o,i,:])
        #pragma unroll
        for (int oi = 0; oi < 8; ++oi) {
            int o = wv * 8 + oi;
            bfr[oi] = *reinterpret_cast<const short8*>(&lw[o * 512 + d * 16 + half * 8]);
            f32x16 z = {};
            f32x16 C = __builtin_amdgcn_mfma_f32_32x32x16_bf16(afr, bfr[oi], z, 0, 0, 0);
            float bvp[16];
            #pragma unroll
            for (int r = 0; r < 16; ++r) {
                int b = (r & 3) + 8 * (r >> 2) + 4 * half;
                float vv = vin[((size_t)o * B_ + b) * OD_ + d];
                bvp[r] = C[r] * vv;
            }
            #pragma unroll
            for (int m = 1; m <= 16; m <<= 1) {
                #pragma unroll
                for (int r = 0; r < 16; ++r)
                    bvp[r] += __shfl_xor(bvp[r], m, 32);
            }
            if ((lane & 31) == 0) {
                #pragma unroll
                for (int r = 0; r < 16; ++r) {
                    int b = (r & 3) + 8 * (r >> 2) + 4 * half;
                    blds[b * ON_ + o] = bvp[r];
                }
            }
        }
        __syncthreads();

        // softmax over o for each (b): 512 threads x 4 slots
        {
            int o = t & 63, bq = t >> 6;
            #pragma unroll
            for (int j = 0; j < 4; ++j) {
                int b = bq + 8 * j;
                float v = blds[b * ON_ + o];
                float m = v;
                #pragma unroll
                for (int mm = 1; mm <= 32; mm <<= 1) m = fmaxf(m, __shfl_xor(m, mm, 64));
                float e = __expf(v - m);
                float ssum = e;
                #pragma unroll
                for (int mm = 1; mm <= 32; mm <<= 1) ssum += __shfl_xor(ssum, mm, 64);
                clds[b * ON_ + o] = e / ssum;
            }
        }
        __syncthreads();

        // phase B: S_acc += c * xhat (re-issue MFMA from kept fragments)
        #pragma unroll
        for (int oi = 0; oi < 8; ++oi) {
            int o = wv * 8 + oi;
            f32x16 z = {};
            f32x16 C = __builtin_amdgcn_mfma_f32_32x32x16_bf16(afr, bfr[oi], z, 0, 0, 0);
            #pragma unroll
            for (int r = 0; r < 16; ++r) {
                int b = (r & 3) + 8 * (r >> 2) + 4 * half;
                float c = clds[b * ON_ + o];
                acc[oi][r] += c * C[r];
            }
        }
        __syncthreads();
    }

    #pragma unroll
    for (int oi = 0; oi < 8; ++oi) {
        int o = wv * 8 + oi;
        #pragma unroll
        for (int r = 0; r < 16; ++r) {
            int b = (r & 3) + 8 * (r >> 2) + 4 * half;
            atomicAdd(&S[((size_t)b * ON_ + o) * OD_ + d], acc[oi][r]);
        }
    }
}

// ---------------- squash + optional add of previous v ----------------
// grid 256 x 256: 2048 rows (b*64+o) x 32 lanes
__global__ __launch_bounds__(256) void squash_k(
    const float* __restrict__ S, const float* __restrict__ addprev,
    float* __restrict__ out, float scale, int out_bod)
{
    int t = threadIdx.x;
    int row = blockIdx.x * 8 + (t >> 5);  // = b*64 + o
    int d = t & 31;
    int b = row >> 6, o = row & 63;
    float s = S[(size_t)row * OD_ + d] * scale;
    float n2 = s * s;
    #pragma unroll
    for (int mm = 1; mm <= 16; mm <<= 1) n2 += __shfl_xor(n2, mm, 32);
    float norm = sqrtf(n2);
    float sc = n2 / ((1.0f + n2) * (norm + 1e-8f));
    float v = sc * s;
    if (addprev) v += addprev[((size_t)o * B_ + b) * OD_ + d];
    if (out_bod)
        out[((size_t)b * ON_ + o) * OD_ + d] = v;
    else
        out[((size_t)o * B_ + b) * OD_ + d] = v;
}

extern "C" void kernel_launch(void* const* d_in, const int* in_sizes, int n_in,
                              void* d_out, int out_size, void* d_ws, size_t ws_size,
                              hipStream_t stream) {
    (void)in_sizes; (void)n_in; (void)out_size; (void)ws_size;
    const float* x = (const float*)d_in[0];
    const float* w = (const float*)d_in[1];
    float* out = (float*)d_out;

    float* S    = (float*)d_ws;          // 65536 f
    float* v0   = S + 65536;             // [o][b][d]
    float* vsum = v0 + 65536;            // [o][b][d]

    const size_t Sbytes = (size_t)65536 * sizeof(float);

    hipMemsetAsync(S, 0, Sbytes, stream);
    pass0_k<<<1024, 256, 0, stream>>>(x, w, S);
    squash_k<<<256, 256, 0, stream>>>(S, nullptr, v0, 1.0f / 64.0f, 0);

    hipMemsetAsync(S, 0, Sbytes, stream);
    pass_route_k<<<256, 512, 0, stream>>>(x, w, v0, S);
    squash_k<<<256, 256, 0, stream>>>(S, v0, vsum, 1.0f, 0);

    hipMemsetAsync(S, 0, Sbytes, stream);
    pass_route_k<<<256, 512, 0, stream>>>(x, w, vsum, S);
    squash_k<<<256, 256, 0, stream>>>(S, nullptr, out, 1.0f, 1);
}

// Round 2
// 661.683 us; speedup vs baseline: 1.2744x; 1.2744x over previous
//
#include <hip/hip_runtime.h>
#include <cstdint>

typedef __attribute__((ext_vector_type(8))) short short8;
typedef __attribute__((ext_vector_type(16))) float f32x16;

#define B_   32
#define IN_  2048
#define ID_  16
#define ON_  64
#define OD_  32
// weight strides (floats): o: 1048576, i: 512, d: 16, k: 1

__device__ __forceinline__ unsigned short f2bf(float f) {
    union { float f; uint32_t u; } c; c.f = f;
    uint32_t u = c.u;
    uint32_t r = (u + 0x7FFFu + ((u >> 16) & 1u)) >> 16;
    return (unsigned short)r;
}
__device__ __forceinline__ unsigned int pack2(float a, float b) {
    return (unsigned int)f2bf(a) | ((unsigned int)f2bf(b) << 16);
}

// ============================ FAST PATH =====================================
// ws layout:
//   wbf  : bf16 weight in MFMA B-fragment order, uint4[(o*2048+i)*64 + lane]   134,217,728 B
//   xbf  : bf16 x in MFMA A-fragment order,      uint4[i*64 + lane]              2,097,152 B
//   part : fp32 partials [slice][b*2048+o*32+d]                                 67,108,864 B
//   v0, vsum : fp32 [o][b][d]                                                     262,144 B each

// ---- pack x -> A-fragment layout: lane holds x[b=lane&31, i, k=half*8+j] ----
__global__ __launch_bounds__(256) void xconv_k(
    const float* __restrict__ x, uint4* __restrict__ xbf)
{
    int t = threadIdx.x, lane = t & 63, wv = t >> 6;
    int i = blockIdx.x * 4 + wv;
    int b = lane & 31, half = lane >> 5;
    const float* g = x + ((size_t)b * IN_ + i) * ID_ + half * 8;
    float4 a = *(const float4*)g;
    float4 c = *(const float4*)(g + 4);
    uint4 p = { pack2(a.x, a.y), pack2(a.z, a.w), pack2(c.x, c.y), pack2(c.z, c.w) };
    xbf[(size_t)i * 64 + lane] = p;
}

// ---- pass0: read w fp32 direct->reg, emit wbf, MFMA-accumulate S0 partials --
// grid 256 = 64 ic (i-chunk 32) x 4 og (16 o). block 1024 = 16 waves x 1 o.
__global__ __launch_bounds__(1024) void pass0_k2(
    const float* __restrict__ w, const uint4* __restrict__ xbf,
    uint4* __restrict__ wbf, float* __restrict__ part)
{
    int t = threadIdx.x, lane = t & 63, wv = t >> 6;
    int og = blockIdx.x & 3, ic = blockIdx.x >> 2;
    int o = og * 16 + wv;
    int d = lane & 31, half = lane >> 5;

    f32x16 acc = {};
    #pragma unroll 4
    for (int ii = 0; ii < 32; ++ii) {
        int i = ic * 32 + ii;
        union { uint4 u; short8 s; } af;
        af.u = xbf[(size_t)i * 64 + lane];
        const float* g = w + ((size_t)o * IN_ + i) * 512 + d * 16 + half * 8;
        float4 a = *(const float4*)g;
        float4 c = *(const float4*)(g + 4);
        union { uint4 u; short8 s; } bf;
        bf.u = (uint4){ pack2(a.x, a.y), pack2(a.z, a.w), pack2(c.x, c.y), pack2(c.z, c.w) };
        wbf[((size_t)o * IN_ + i) * 64 + lane] = bf.u;
        acc = __builtin_amdgcn_mfma_f32_32x32x16_bf16(af.s, bf.s, acc, 0, 0, 0);
    }
    float* dst = part + (size_t)ic * 65536;
    #pragma unroll
    for (int r = 0; r < 16; ++r) {
        int b = (r & 3) + 8 * (r >> 2) + 4 * half;
        dst[(size_t)b * 2048 + o * 32 + d] = acc[r];
    }
}

// ---- routing pass: all-register weight frags, softmax via 16 KB LDS --------
// grid 256 ic (i-chunk 8). block 1024 = 16 waves x 4 o.
__global__ __launch_bounds__(1024) void route_k2(
    const uint4* __restrict__ wbf, const uint4* __restrict__ xbf,
    const float* __restrict__ vin /*[o][b][d]*/, float* __restrict__ part)
{
    __shared__ float blds[B_ * ON_];
    __shared__ float clds[B_ * ON_];

    int t = threadIdx.x, lane = t & 63, wv = t >> 6;
    int ic = blockIdx.x;
    int d = lane & 31, half = lane >> 5;

    f32x16 acc[4] = {};

    for (int ii = 0; ii < 8; ++ii) {
        int i = ic * 8 + ii;
        union { uint4 u; short8 s; } af;
        af.u = xbf[(size_t)i * 64 + lane];
        short8 bfr[4];
        #pragma unroll
        for (int oi = 0; oi < 4; ++oi) {
            int o = wv * 4 + oi;
            union { uint4 u; short8 s; } bb;
            bb.u = wbf[((size_t)o * IN_ + i) * 64 + lane];
            bfr[oi] = bb.s;
        }

        // phase A: logits b[b,o] = dot(v, xhat) ; in-place scale of C
        #pragma unroll
        for (int oi = 0; oi < 4; ++oi) {
            int o = wv * 4 + oi;
            f32x16 z = {};
            f32x16 C = __builtin_amdgcn_mfma_f32_32x32x16_bf16(af.s, bfr[oi], z, 0, 0, 0);
            const float* vp = vin + (size_t)o * (B_ * OD_) + d;
            #pragma unroll
            for (int r = 0; r < 16; ++r) {
                int b = (r & 3) + 8 * (r >> 2) + 4 * half;
                C[r] *= vp[b * 32];
            }
            #pragma unroll
            for (int m = 1; m <= 16; m <<= 1) {
                #pragma unroll
                for (int r = 0; r < 16; ++r) C[r] += __shfl_xor(C[r], m, 32);
            }
            if ((lane & 31) == 0) {
                #pragma unroll
                for (int r = 0; r < 16; ++r) {
                    int b = (r & 3) + 8 * (r >> 2) + 4 * half;
                    blds[b * ON_ + o] = C[r];
                }
            }
        }
        __syncthreads();

        // softmax over o for each b: 1024 threads x 2 slots
        {
            int o = t & 63, bq = t >> 6;
            #pragma unroll
            for (int j = 0; j < 2; ++j) {
                int b = bq + 16 * j;
                float vl = blds[b * ON_ + o];
                float m = vl;
                #pragma unroll
                for (int mm = 1; mm <= 32; mm <<= 1) m = fmaxf(m, __shfl_xor(m, mm, 64));
                float e = __expf(vl - m);
                float ss = e;
                #pragma unroll
                for (int mm = 1; mm <= 32; mm <<= 1) ss += __shfl_xor(ss, mm, 64);
                clds[b * ON_ + o] = e / ss;
            }
        }
        __syncthreads();

        // phase B: re-issue MFMA, accumulate c * xhat
        #pragma unroll
        for (int oi = 0; oi < 4; ++oi) {
            int o = wv * 4 + oi;
            f32x16 z = {};
            f32x16 C = __builtin_amdgcn_mfma_f32_32x32x16_bf16(af.s, bfr[oi], z, 0, 0, 0);
            #pragma unroll
            for (int r = 0; r < 16; ++r) {
                int b = (r & 3) + 8 * (r >> 2) + 4 * half;
                acc[oi][r] += clds[b * ON_ + o] * C[r];
            }
        }
    }

    float* dst = part + (size_t)ic * 65536;
    #pragma unroll
    for (int oi = 0; oi < 4; ++oi) {
        int o = wv * 4 + oi;
        #pragma unroll
        for (int r = 0; r < 16; ++r) {
            int b = (r & 3) + 8 * (r >> 2) + 4 * half;
            dst[(size_t)b * 2048 + o * 32 + d] = acc[oi][r];
        }
    }
}

// ---- reduce partials + squash (+optional add prev v) -----------------------
// grid 256, block 256 = 4 waves x 2 rows; row = b*64+o
__global__ __launch_bounds__(256) void reduce_squash_k(
    const float* __restrict__ part, int nslices, float scale,
    const float* __restrict__ addprev, float* __restrict__ outv, int out_bod)
{
    int t = threadIdx.x, lane = t & 63, wv = t >> 6;
    int row = blockIdx.x * 8 + wv * 2 + (lane >> 5);
    int d = lane & 31;
    const float* p = part + (size_t)row * 32 + d;
    float s0 = 0, s1 = 0, s2 = 0, s3 = 0;
    for (int s = 0; s < nslices; s += 4) {
        s0 += p[(size_t)(s + 0) * 65536];
        s1 += p[(size_t)(s + 1) * 65536];
        s2 += p[(size_t)(s + 2) * 65536];
        s3 += p[(size_t)(s + 3) * 65536];
    }
    float sv = ((s0 + s1) + (s2 + s3)) * scale;
    float n2 = sv * sv;
    #pragma unroll
    for (int m = 1; m <= 16; m <<= 1) n2 += __shfl_xor(n2, m, 32);
    float norm = sqrtf(n2);
    float sc = n2 / ((1.0f + n2) * (norm + 1e-8f));
    float v = sc * sv;
    int b = row >> 6, o = row & 63;
    if (addprev) v += addprev[((size_t)o * B_ + b) * OD_ + d];
    if (out_bod) outv[(size_t)row * OD_ + d] = v;
    else         outv[((size_t)o * B_ + b) * OD_ + d] = v;
}

// ============================ LEGACY PATH (round-1, proven) =================

__global__ __launch_bounds__(256, 4) void pass0_k(
    const float* __restrict__ x, const float* __restrict__ w, float* __restrict__ S)
{
    __shared__ __align__(16) unsigned short lw[16 * 512];
    __shared__ __align__(16) unsigned short lx[512];

    const int t = threadIdx.x, lane = t & 63, wv = t >> 6;
    const int bx = blockIdx.x;
    const int ic = bx & 255, og = bx >> 8;
    const int o0 = og * 16;
    const int d = lane & 31, half = lane >> 5;

    f32x16 acc[4] = {};

    for (int i = ic * 8; i < ic * 8 + 8; ++i) {
        #pragma unroll
        for (int r = 0; r < 4; ++r) {
            int cidx = r * 256 + t;
            int ol = cidx >> 6, j8 = cidx & 63;
            const float* g = w + (size_t)(o0 + ol) * 1048576 + (size_t)i * 512 + j8 * 8;
            float4 a = *(const float4*)g;
            float4 b2 = *(const float4*)(g + 4);
            uint4 val = { pack2(a.x, a.y), pack2(a.z, a.w), pack2(b2.x, b2.y), pack2(b2.z, b2.w) };
            *reinterpret_cast<uint4*>(&lw[ol * 512 + j8 * 8]) = val;
        }
        if (t < 128) {
            int b = t >> 2, kq = t & 3;
            float4 a = *(const float4*)(x + ((size_t)b * IN_ + i) * ID_ + kq * 4);
            uint2 val = { pack2(a.x, a.y), pack2(a.z, a.w) };
            *reinterpret_cast<uint2*>(&lx[b * 16 + kq * 4]) = val;
        }
        __syncthreads();

        short8 afr = *reinterpret_cast<const short8*>(&lx[(lane & 31) * 16 + half * 8]);
        #pragma unroll
        for (int oi = 0; oi < 4; ++oi) {
            int ol = wv * 4 + oi;
            short8 bfr = *reinterpret_cast<const short8*>(&lw[ol * 512 + d * 16 + half * 8]);
            acc[oi] = __builtin_amdgcn_mfma_f32_32x32x16_bf16(afr, bfr, acc[oi], 0, 0, 0);
        }
        __syncthreads();
    }

    #pragma unroll
    for (int oi = 0; oi < 4; ++oi) {
        int o = o0 + wv * 4 + oi;
        #pragma unroll
        for (int r = 0; r < 16; ++r) {
            int b = (r & 3) + 8 * (r >> 2) + 4 * half;
            atomicAdd(&S[((size_t)b * ON_ + o) * OD_ + d], acc[oi][r]);
        }
    }
}

__global__ __launch_bounds__(512, 2) void pass_route_k(
    const float* __restrict__ x, const float* __restrict__ w,
    const float* __restrict__ vin, float* __restrict__ S)
{
    __shared__ __align__(16) unsigned short lw[64 * 512];
    __shared__ __align__(16) unsigned short lx[512];
    __shared__ float blds[B_ * ON_];
    __shared__ float clds[B_ * ON_];

    const int t = threadIdx.x, lane = t & 63, wv = t >> 6;
    const int ic = blockIdx.x;
    const int d = lane & 31, half = lane >> 5;

    f32x16 acc[8] = {};

    for (int i = ic * 8; i < ic * 8 + 8; ++i) {
        #pragma unroll
        for (int r = 0; r < 8; ++r) {
            int cidx = r * 512 + t;
            int ol = cidx >> 6, j8 = cidx & 63;
            const float* g = w + (size_t)ol * 1048576 + (size_t)i * 512 + j8 * 8;
            float4 a = *(const float4*)g;
            float4 b2 = *(const float4*)(g + 4);
            uint4 val = { pack2(a.x, a.y), pack2(a.z, a.w), pack2(b2.x, b2.y), pack2(b2.z, b2.w) };
            *reinterpret_cast<uint4*>(&lw[ol * 512 + j8 * 8]) = val;
        }
        if (t < 128) {
            int b = t >> 2, kq = t & 3;
            float4 a = *(const float4*)(x + ((size_t)b * IN_ + i) * ID_ + kq * 4);
            uint2 val = { pack2(a.x, a.y), pack2(a.z, a.w) };
            *reinterpret_cast<uint2*>(&lx[b * 16 + kq * 4]) = val;
        }
        __syncthreads();

        short8 afr = *reinterpret_cast<const short8*>(&lx[(lane & 31) * 16 + half * 8]);
        short8 bfr[8];

        #pragma unroll
        for (int oi = 0; oi < 8; ++oi) {
            int o = wv * 8 + oi;
            bfr[oi] = *reinterpret_cast<const short8*>(&lw[o * 512 + d * 16 + half * 8]);
            f32x16 z = {};
            f32x16 C = __builtin_amdgcn_mfma_f32_32x32x16_bf16(afr, bfr[oi], z, 0, 0, 0);
            float bvp[16];
            #pragma unroll
            for (int r = 0; r < 16; ++r) {
                int b = (r & 3) + 8 * (r >> 2) + 4 * half;
                float vv = vin[((size_t)o * B_ + b) * OD_ + d];
                bvp[r] = C[r] * vv;
            }
            #pragma unroll
            for (int m = 1; m <= 16; m <<= 1) {
                #pragma unroll
                for (int r = 0; r < 16; ++r)
                    bvp[r] += __shfl_xor(bvp[r], m, 32);
            }
            if ((lane & 31) == 0) {
                #pragma unroll
                for (int r = 0; r < 16; ++r) {
                    int b = (r & 3) + 8 * (r >> 2) + 4 * half;
                    blds[b * ON_ + o] = bvp[r];
                }
            }
        }
        __syncthreads();

        {
            int o = t & 63, bq = t >> 6;
            #pragma unroll
            for (int j = 0; j < 4; ++j) {
                int b = bq + 8 * j;
                float v = blds[b * ON_ + o];
                float m = v;
                #pragma unroll
                for (int mm = 1; mm <= 32; mm <<= 1) m = fmaxf(m, __shfl_xor(m, mm, 64));
                float e = __expf(v - m);
                float ssum = e;
                #pragma unroll
                for (int mm = 1; mm <= 32; mm <<= 1) ssum += __shfl_xor(ssum, mm, 64);
                clds[b * ON_ + o] = e / ssum;
            }
        }
        __syncthreads();

        #pragma unroll
        for (int oi = 0; oi < 8; ++oi) {
            int o = wv * 8 + oi;
            f32x16 z = {};
            f32x16 C = __builtin_amdgcn_mfma_f32_32x32x16_bf16(afr, bfr[oi], z, 0, 0, 0);
            #pragma unroll
            for (int r = 0; r < 16; ++r) {
                int b = (r & 3) + 8 * (r >> 2) + 4 * half;
                acc[oi][r] += clds[b * ON_ + o] * C[r];
            }
        }
        __syncthreads();
    }

    #pragma unroll
    for (int oi = 0; oi < 8; ++oi) {
        int o = wv * 8 + oi;
        #pragma unroll
        for (int r = 0; r < 16; ++r) {
            int b = (r & 3) + 8 * (r >> 2) + 4 * half;
            atomicAdd(&S[((size_t)b * ON_ + o) * OD_ + d], acc[oi][r]);
        }
    }
}

__global__ __launch_bounds__(256) void squash_k(
    const float* __restrict__ S, const float* __restrict__ addprev,
    float* __restrict__ out, float scale, int out_bod)
{
    int t = threadIdx.x;
    int row = blockIdx.x * 8 + (t >> 5);
    int d = t & 31;
    int b = row >> 6, o = row & 63;
    float s = S[(size_t)row * OD_ + d] * scale;
    float n2 = s * s;
    #pragma unroll
    for (int mm = 1; mm <= 16; mm <<= 1) n2 += __shfl_xor(n2, mm, 32);
    float norm = sqrtf(n2);
    float sc = n2 / ((1.0f + n2) * (norm + 1e-8f));
    float v = sc * s;
    if (addprev) v += addprev[((size_t)o * B_ + b) * OD_ + d];
    if (out_bod)
        out[((size_t)b * ON_ + o) * OD_ + d] = v;
    else
        out[((size_t)o * B_ + b) * OD_ + d] = v;
}

// ============================ LAUNCHER ======================================

extern "C" void kernel_launch(void* const* d_in, const int* in_sizes, int n_in,
                              void* d_out, int out_size, void* d_ws, size_t ws_size,
                              hipStream_t stream) {
    (void)in_sizes; (void)n_in; (void)out_size;
    const float* x = (const float*)d_in[0];
    const float* w = (const float*)d_in[1];
    float* out = (float*)d_out;

    const size_t WBF_B  = 134217728;   // 64*2048*1024
    const size_t XBF_B  = 2097152;     // 2048*1024
    const size_t PART_B = 67108864;    // 256*65536*4
    const size_t V_B    = 262144;
    const size_t NEED   = WBF_B + XBF_B + PART_B + 2 * V_B;

    if (ws_size >= NEED) {
        uint8_t* wsb = (uint8_t*)d_ws;
        uint4* wbf  = (uint4*)wsb;
        uint4* xbf  = (uint4*)(wsb + WBF_B);
        float* part = (float*)(wsb + WBF_B + XBF_B);
        float* v0   = (float*)(wsb + WBF_B + XBF_B + PART_B);
        float* vsum = (float*)(wsb + WBF_B + XBF_B + PART_B + V_B);

        xconv_k<<<512, 256, 0, stream>>>(x, xbf);
        pass0_k2<<<256, 1024, 0, stream>>>(w, xbf, wbf, part);
        reduce_squash_k<<<256, 256, 0, stream>>>(part, 64, 1.0f / 64.0f, nullptr, v0, 0);
        route_k2<<<256, 1024, 0, stream>>>(wbf, xbf, v0, part);
        reduce_squash_k<<<256, 256, 0, stream>>>(part, 256, 1.0f, v0, vsum, 0);
        route_k2<<<256, 1024, 0, stream>>>(wbf, xbf, vsum, part);
        reduce_squash_k<<<256, 256, 0, stream>>>(part, 256, 1.0f, nullptr, out, 1);
    } else {
        // legacy (round-1) path — needs only 768 KB of ws
        float* S    = (float*)d_ws;
        float* v0   = S + 65536;
        float* vsum = v0 + 65536;
        const size_t Sbytes = (size_t)65536 * sizeof(float);

        hipMemsetAsync(S, 0, Sbytes, stream);
        pass0_k<<<1024, 256, 0, stream>>>(x, w, S);
        squash_k<<<256, 256, 0, stream>>>(S, nullptr, v0, 1.0f / 64.0f, 0);

        hipMemsetAsync(S, 0, Sbytes, stream);
        pass_route_k<<<256, 512, 0, stream>>>(x, w, v0, S);
        squash_k<<<256, 256, 0, stream>>>(S, v0, vsum, 1.0f, 0);

        hipMemsetAsync(S, 0, Sbytes, stream);
        pass_route_k<<<256, 512, 0, stream>>>(x, w, vsum, S);
        squash_k<<<256, 256, 0, stream>>>(S, nullptr, out, 1.0f, 1);
    }
}